// Round 1
// baseline (1802.278 us; speedup 1.0000x reference)
//
#include <hip/hip_runtime.h>

// GraphConv: out = LeakyReLU( (sum_k att_k A_k) @ (inputs@w + b), 0.2 )
// N=10000, C_in=C_out=128, N_ADJ=3, all fp32.
//
// Measured decomposition (R0 theory): total 1779us = 2 x ~750us harness ws-poison
// fills (uncontrollable, 4.8GB @ 80% HBM peak) + ~280us of our kernels.
// Controllable floor: 1.2GB adjacency stream @ 6.3TB/s = ~190us.
// This revision: (1) inner loop reads s_mix as float4 per 4-m group -> LDS issue
// < VALU issue; (2) nontemporal adjacency loads (single-use, keep L2 for support);
// (3) support kernel uses float4 w loads + 2x4 register tile.

#define NN 10000
#define CC 128
#define NEG_SLOPE 0.2f

#define BN 32            // output rows per block (kernel 2)
#define BM 64            // m-chunk (K of big matmul) per staging step
#define SUP_ROWS 10048   // support rows padded to multiple of BM
#define NCHUNK 157       // ceil(10000/64)
#define SPLIT_CH 79      // z=0 does chunks [0,79), z=1 does [79,157)

typedef float f4 __attribute__((ext_vector_type(4)));

// ---------------- kernel 1: support = inputs @ w + b ----------------
__global__ __launch_bounds__(256)
void support_kernel(const float* __restrict__ in, const float* __restrict__ w,
                    const float* __restrict__ b, float* __restrict__ sup) {
    __shared__ float s_in[16][CC];          // 8 KB
    const int tid = threadIdx.x;
    const int n0 = blockIdx.x * 16;         // 625 blocks * 16 rows = 10000 exact

    // stage 16 input rows (float4-coalesced)
    #pragma unroll
    for (int i = 0; i < 2; ++i) {
        int f4i = tid + i * 256;
        int r = f4i >> 5, c4 = (f4i & 31) * 4;
        *(float4*)&s_in[r][c4] = *(const float4*)&in[(n0 + r) * CC + c4];
    }
    __syncthreads();

    const int cg = tid & 31;                // cols cg*4 .. cg*4+3
    const int rg = tid >> 5;                // rows rg*2, rg*2+1
    float acc0x = 0.f, acc0y = 0.f, acc0z = 0.f, acc0w = 0.f;
    float acc1x = 0.f, acc1y = 0.f, acc1z = 0.f, acc1w = 0.f;

    #pragma unroll 8
    for (int k = 0; k < CC; ++k) {
        float4 wv = *(const float4*)&w[k * CC + cg * 4];   // L2-resident (64 KB)
        float x0 = s_in[rg * 2 + 0][k];                    // LDS broadcast
        float x1 = s_in[rg * 2 + 1][k];
        acc0x += x0 * wv.x; acc0y += x0 * wv.y;
        acc0z += x0 * wv.z; acc0w += x0 * wv.w;
        acc1x += x1 * wv.x; acc1y += x1 * wv.y;
        acc1z += x1 * wv.z; acc1w += x1 * wv.w;
    }
    float4 bv = *(const float4*)&b[cg * 4];
    float4 o0, o1;
    o0.x = acc0x + bv.x; o0.y = acc0y + bv.y; o0.z = acc0z + bv.z; o0.w = acc0w + bv.w;
    o1.x = acc1x + bv.x; o1.y = acc1y + bv.y; o1.z = acc1z + bv.z; o1.w = acc1w + bv.w;
    *(float4*)&sup[(n0 + rg * 2 + 0) * CC + cg * 4] = o0;
    *(float4*)&sup[(n0 + rg * 2 + 1) * CC + cg * 4] = o1;
}

// ------- kernel 2: partial[z] = (att-mixed adj chunk-range) @ support -------
__global__ __launch_bounds__(256)
void gc_main(const float* __restrict__ adj, const float* __restrict__ att_p,
             const float* __restrict__ sup, float* __restrict__ pbase) {
    __shared__ float s_sup[BM][CC];         // 32 KB
    __shared__ float s_mix[BN][BM + 4];     // 8.5 KB, +4 pad keeps float4 align

    const int tid = threadIdx.x;
    const int n0 = blockIdx.x * BN;         // 313 blocks cover 10016 rows
    const int z  = blockIdx.y;
    const int ch_begin = z ? SPLIT_CH : 0;
    const int ch_end   = z ? NCHUNK   : SPLIT_CH;
    float* __restrict__ part = pbase + (size_t)z * NN * CC;

    const float att0 = att_p[0], att1 = att_p[1], att2 = att_p[2];
    const float* A0 = adj;
    const float* A1 = adj + (long long)NN * NN;
    const float* A2 = adj + 2LL * NN * NN;

    const int cg = tid & 31;                // 4 cols: cg*4 .. cg*4+3
    const int ng = tid >> 5;                // 4 rows: ng*4 .. ng*4+3
    float4 acc[4];
    #pragma unroll
    for (int i = 0; i < 4; ++i) acc[i] = make_float4(0.f, 0.f, 0.f, 0.f);

    for (int ch = ch_begin; ch < ch_end; ++ch) {
        const int m0 = ch * BM;
        __syncthreads();                    // previous compute done before restage

        // stage support chunk: rows m0..m0+63 (zero-padded past 10000)
        #pragma unroll
        for (int i = 0; i < 8; ++i) {
            int f4i = tid + i * 256;
            int r = f4i >> 5, c4 = (f4i & 31) * 4;
            *(float4*)&s_sup[r][c4] = *(const float4*)&sup[(m0 + r) * CC + c4];
        }
        // stage attention-mixed adjacency tile [BN x BM]; adjacency is
        // single-use 1.2 GB -> nontemporal so it doesn't evict support/partials.
        #pragma unroll
        for (int i = 0; i < 2; ++i) {
            int f4i = tid + i * 256;
            int row = f4i >> 4, mc = (f4i & 15) * 4;
            int n = n0 + row, m = m0 + mc;
            f4 v = 0.f;
            if (n < NN && m < NN) {
                long long off = (long long)n * NN + m;
                f4 a0 = __builtin_nontemporal_load((const f4*)(A0 + off));
                f4 a1 = __builtin_nontemporal_load((const f4*)(A1 + off));
                f4 a2 = __builtin_nontemporal_load((const f4*)(A2 + off));
                v = att0 * a0 + att1 * a1 + att2 * a2;
            }
            *(f4*)&s_mix[row][mc] = v;
        }
        __syncthreads();

        // compute: 4n x 4c register tile, m processed in groups of 4.
        // Per 4-m group: 8x ds_read_b128 (~96 cyc issue) vs 64 FMA (128 cyc)
        // -> VALU-bound inner loop (was LDS-issue-bound with 4x b32/m).
        #pragma unroll 4
        for (int mm = 0; mm < BM; mm += 4) {
            float am0[4], am1[4], am2[4], am3[4];
            *(f4*)am0 = *(const f4*)&s_mix[ng * 4 + 0][mm];
            *(f4*)am1 = *(const f4*)&s_mix[ng * 4 + 1][mm];
            *(f4*)am2 = *(const f4*)&s_mix[ng * 4 + 2][mm];
            *(f4*)am3 = *(const f4*)&s_mix[ng * 4 + 3][mm];
            #pragma unroll
            for (int j = 0; j < 4; ++j) {
                float4 sv = *(const float4*)&s_sup[mm + j][cg * 4];
                float b0 = am0[j], b1 = am1[j], b2 = am2[j], b3 = am3[j];
                acc[0].x += b0 * sv.x; acc[0].y += b0 * sv.y;
                acc[0].z += b0 * sv.z; acc[0].w += b0 * sv.w;
                acc[1].x += b1 * sv.x; acc[1].y += b1 * sv.y;
                acc[1].z += b1 * sv.z; acc[1].w += b1 * sv.w;
                acc[2].x += b2 * sv.x; acc[2].y += b2 * sv.y;
                acc[2].z += b2 * sv.z; acc[2].w += b2 * sv.w;
                acc[3].x += b3 * sv.x; acc[3].y += b3 * sv.y;
                acc[3].z += b3 * sv.z; acc[3].w += b3 * sv.w;
            }
        }
    }

    #pragma unroll
    for (int i = 0; i < 4; ++i) {
        int n = n0 + ng * 4 + i;
        if (n < NN)
            *(float4*)&part[(size_t)n * CC + cg * 4] = acc[i];
    }
}

// ---------------- kernel 3: out = LeakyReLU(p0 + p1) ----------------
__global__ __launch_bounds__(256)
void combine_kernel(const float4* __restrict__ p0, const float4* __restrict__ p1,
                    float4* __restrict__ out) {
    int idx = blockIdx.x * 256 + threadIdx.x;   // 1250 blocks * 256 = 320000 exact
    float4 a = p0[idx];
    float4 b = p1[idx];
    float4 o;
    o.x = a.x + b.x; o.y = a.y + b.y; o.z = a.z + b.z; o.w = a.w + b.w;
    o.x = (o.x >= 0.f) ? o.x : NEG_SLOPE * o.x;
    o.y = (o.y >= 0.f) ? o.y : NEG_SLOPE * o.y;
    o.z = (o.z >= 0.f) ? o.z : NEG_SLOPE * o.z;
    o.w = (o.w >= 0.f) ? o.w : NEG_SLOPE * o.w;
    out[idx] = o;
}

extern "C" void kernel_launch(void* const* d_in, const int* in_sizes, int n_in,
                              void* d_out, int out_size, void* d_ws, size_t ws_size,
                              hipStream_t stream) {
    const float* inputs = (const float*)d_in[0];  // [10000,128]
    const float* adj    = (const float*)d_in[1];  // [3,10000,10000]
    const float* att    = (const float*)d_in[2];  // [3]
    const float* w      = (const float*)d_in[3];  // [128,128]
    const float* b      = (const float*)d_in[4];  // [128]
    float* out = (float*)d_out;                   // [10000,128]

    // ws layout: support[10048][128] | p0[10000][128] | p1[10000][128]  (~15.5 MB)
    float* sup = (float*)d_ws;
    float* p0  = sup + (size_t)SUP_ROWS * CC;

    // zero the padded support rows (ws is poisoned 0xAA before every launch)
    hipMemsetAsync(sup + (size_t)NN * CC, 0,
                   (size_t)(SUP_ROWS - NN) * CC * sizeof(float), stream);

    support_kernel<<<625, 256, 0, stream>>>(inputs, w, b, sup);
    gc_main<<<dim3(313, 2), 256, 0, stream>>>(adj, att, sup, p0);
    combine_kernel<<<1250, 256, 0, stream>>>(
        (const float4*)p0, (const float4*)(p0 + (size_t)NN * CC), (float4*)out);
}